// Round 13
// baseline (196.465 us; speedup 1.0000x reference)
//
#include <hip/hip_runtime.h>
#include <hip/hip_cooperative_groups.h>

namespace cg = cooperative_groups;

// MergeLayer: out = sigmoid(relu([z[e0]; z[e1]] @ W1 + b1) @ W2 + b2)
// Factored: g = z @ Wcat (+b1 on gi half)  -- node GEMM via bf16 MFMA
//           out[k] = sigmoid(dot(relu(si*qi[e0]+sj*qj[e1]), W2) + b2)
//
// Round-13: single cooperative dispatch. R12's budget: fill ~45 (fixed) +
// wt 3 + node ~25 + edge ~22 + LAUNCH GAPS ~15-19. Node and edge are both
// within ~2x of their memory walls (edge at the 2-lines/edge floor); the
// gaps are the largest untouched term. Fusion: wt + node + edge in ONE
// hipLaunchCooperativeKernel (512 blocks x 512 thr, 2 blocks/CU) with two
// grid.sync()s. Inner code bit-identical to R12. If the cooperative launch
// fails for any reason -> fall back to the proven R12 3-kernel pipeline.
//
// ws layout: gqi (N*128 s8) | gqj (N*128 s8) | sci (N f32) | scj | Wt (64KB)

#define DD 128

typedef __attribute__((ext_vector_type(8))) short short8;
typedef __attribute__((ext_vector_type(4))) float floatx4;

static __device__ __forceinline__ unsigned short f2bf(float f) {
  unsigned int u = __builtin_bit_cast(unsigned int, f);
  u += 0x7fffu + ((u >> 16) & 1u);   // round-to-nearest-even
  return (unsigned short)(u >> 16);
}

// ============================ fused cooperative kernel =======================
__global__ __launch_bounds__(512, 4) void fused_all(
    const float* __restrict__ z, const int* __restrict__ e,
    const float* __restrict__ W1, const float* __restrict__ b1,
    const float* __restrict__ W2, const float* __restrict__ b2,
    float* __restrict__ out, signed char* __restrict__ gqi,
    signed char* __restrict__ gqj, float* __restrict__ sci,
    float* __restrict__ scj, unsigned short* __restrict__ Wt,
    int n_nodes, int E) {
  cg::grid_group grid = cg::this_grid();
  __shared__ __align__(16) unsigned short zb[64 * 136];   // 17.4 KB
  __shared__ unsigned int ep[2 * 64 * 33];                // 16.9 KB
  __shared__ unsigned int smax[2][64];
  const int tid = threadIdx.x;

  // ---- phase 0: Wt[c][k] = Wcat[k][c] as bf16 (16 blocks cover 8192 slots)
  if (blockIdx.x < 16) {
    const int g = blockIdx.x * 512 + tid;  // 0..8191
    const int c = g >> 5;                  // 0..255
    const int kq = (g & 31) * 4;           // 0..124
    const float* src = (c < 128) ? (W1 + c) : (W1 + 128 * 128 + (c - 128));
    ushort4 o;
    o.x = f2bf(src[(size_t)(kq + 0) * 128]);
    o.y = f2bf(src[(size_t)(kq + 1) * 128]);
    o.z = f2bf(src[(size_t)(kq + 2) * 128]);
    o.w = f2bf(src[(size_t)(kq + 3) * 128]);
    *(ushort4*)&Wt[c * 128 + kq] = o;
  }
  grid.sync();

  // ---- phase 1: node GEMM, tiles grid-strided (R12 body, frags hoisted) ----
  const int w = tid >> 6, lane = tid & 63;
  const int l15 = lane & 15, quad = lane >> 4;
  const int ntiles = (n_nodes + 63) >> 6;

  short8 a[2][4];
#pragma unroll
  for (int tt = 0; tt < 2; ++tt) {
    const unsigned short* wrow =
        Wt + (size_t)((w * 2 + tt) * 16 + l15) * 128 + quad * 8;
#pragma unroll
    for (int s = 0; s < 4; ++s) a[tt][s] = *(const short8*)(wrow + s * 32);
  }
  floatx4 biasv[2];
#pragma unroll
  for (int tt = 0; tt < 2; ++tt) {
    floatx4 b = {0.f, 0.f, 0.f, 0.f};
    if (w < 4) {
      float4 b4 = *(const float4*)&b1[(w * 2 + tt) * 16 + quad * 4];
      b[0] = b4.x; b[1] = b4.y; b[2] = b4.z; b[3] = b4.w;
    }
    biasv[tt] = b;
  }
  const int half = w >> 2;
  const int cbase = (w & 3) * 32;

  for (int tile = blockIdx.x; tile < ntiles; tile += gridDim.x) {
    const int nb = tile * 64;
    if (tid < 128) smax[tid >> 6][tid & 63] = 0u;
#pragma unroll
    for (int i = 0; i < 4; ++i) {
      int q = tid + i * 512;
      int nl = q >> 5;
      int node = nb + nl; if (node >= n_nodes) node = n_nodes - 1;
      float4 v = ((const float4*)z)[(size_t)node * 32 + (q & 31)];
      ushort4 o;
      o.x = f2bf(v.x); o.y = f2bf(v.y); o.z = f2bf(v.z); o.w = f2bf(v.w);
      *(ushort4*)&zb[nl * 136 + (q & 31) * 4] = o;
    }
    floatx4 acc[2][4];
#pragma unroll
    for (int tt = 0; tt < 2; ++tt)
#pragma unroll
      for (int nt = 0; nt < 4; ++nt) acc[tt][nt] = biasv[tt];
    __syncthreads();

#pragma unroll
    for (int nt = 0; nt < 4; ++nt) {
      short8 bz[4];
#pragma unroll
      for (int s = 0; s < 4; ++s)
        bz[s] = *(const short8*)&zb[(nt * 16 + l15) * 136 + s * 32 + quad * 8];
#pragma unroll
      for (int tt = 0; tt < 2; ++tt)
#pragma unroll
        for (int s = 0; s < 4; ++s)
          acc[tt][nt] = __builtin_amdgcn_mfma_f32_16x16x32_bf16(
              a[tt][s], bz[s], acc[tt][nt], 0, 0, 0);
    }

    // absmax -> quantize -> coalesced copy-out (R12 epilogue)
#pragma unroll
    for (int nt = 0; nt < 4; ++nt) {
      float m = 0.f;
#pragma unroll
      for (int tt = 0; tt < 2; ++tt)
#pragma unroll
        for (int r = 0; r < 4; ++r) m = fmaxf(m, fabsf(acc[tt][nt][r]));
      m = fmaxf(m, __shfl_xor(m, 16));
      m = fmaxf(m, __shfl_xor(m, 32));
      if (lane < 16)
        atomicMax(&smax[half][nt * 16 + lane], __float_as_uint(m));
    }
    __syncthreads();
#pragma unroll
    for (int nt = 0; nt < 4; ++nt) {
      const int node_l = nt * 16 + l15;
      const float am = __uint_as_float(smax[half][node_l]);
      const float inv = (am > 0.f) ? 127.f / am : 0.f;
#pragma unroll
      for (int tt = 0; tt < 2; ++tt) {
        unsigned int v = 0;
#pragma unroll
        for (int r = 0; r < 4; ++r) {
          const int q = (int)rintf(acc[tt][nt][r] * inv);
          v |= ((unsigned int)(q & 0xff)) << (8 * r);
        }
        ep[half * 2112 + node_l * 33 + ((cbase + tt * 16 + quad * 4) >> 2)] = v;
      }
    }
    __syncthreads();
    {
      const int hh = tid >> 8;
      const int sub = tid & 255;
      const int nl = sub >> 2;
      const int c32 = (sub & 3) * 32;
      const int node = nb + nl;
      const unsigned int* rp = &ep[hh * 2112 + nl * 33 + (c32 >> 2)];
      uint4 o0, o1;
      o0.x = rp[0]; o0.y = rp[1]; o0.z = rp[2]; o0.w = rp[3];
      o1.x = rp[4]; o1.y = rp[5]; o1.z = rp[6]; o1.w = rp[7];
      if (node < n_nodes) {
        signed char* dq = hh ? gqj : gqi;
        uint4* gp = (uint4*)(dq + (size_t)node * 128 + c32);
        gp[0] = o0; gp[1] = o1;
      }
      if (tid < 128) {
        const int h2 = tid >> 6, n2 = tid & 63;
        const int node2 = nb + n2;
        if (node2 < n_nodes) {
          const float amv = __uint_as_float(smax[h2][n2]);
          (h2 ? scj : sci)[node2] = amv * (1.f / 127.f);
        }
      }
    }
    __syncthreads();   // protect smax/ep before next iteration
  }
  grid.sync();

  // ---- phase 2: edge MLP (R12 loop, 64 groups/block striding) ----
  {
    const int p = tid & 7;
    const float4* wv = (const float4*)W2;
    float4 W[4];
#pragma unroll
    for (int k = 0; k < 4; ++k) W[k] = wv[p * 4 + k];
    const float bias2 = b2[0];
    const int stride = gridDim.x * 64;  // 64 edges per block per iteration
    for (int edge = blockIdx.x * 64 + (tid >> 3); edge < E; edge += stride) {
      const int i = e[edge];
      const int j = e[E + edge];
      const float si = sci[i];
      const float sj = scj[j];
      const uint4 qa = ((const uint4*)(gqi + (size_t)i * 128))[p];
      const uint4 qb = ((const uint4*)(gqj + (size_t)j * 128))[p];
      const unsigned int ua[4] = {qa.x, qa.y, qa.z, qa.w};
      const unsigned int ub[4] = {qb.x, qb.y, qb.z, qb.w};
      float acc = 0.f;
#pragma unroll
      for (int k = 0; k < 4; ++k) {
        const float wk[4] = {W[k].x, W[k].y, W[k].z, W[k].w};
#pragma unroll
        for (int b = 0; b < 4; ++b) {
          const float af = (float)(int)(signed char)(ua[k] >> (8 * b));
          const float bf = (float)(int)(signed char)(ub[k] >> (8 * b));
          const float h = fmaf(si, af, sj * bf);
          acc = fmaf(fmaxf(h, 0.f), wk[b], acc);
        }
      }
      acc += __shfl_xor(acc, 1);
      acc += __shfl_xor(acc, 2);
      acc += __shfl_xor(acc, 4);
      if (p == 0) out[edge] = 1.f / (1.f + __expf(-(acc + bias2)));
    }
  }
}

// ======================= fallback pipeline (R12, proven) =====================
__global__ __launch_bounds__(256) void wt_build(
    const float* __restrict__ W1, unsigned short* __restrict__ Wt) {
  const int g = blockIdx.x * 256 + threadIdx.x;
  const int c = g >> 5;
  const int kq = (g & 31) * 4;
  const float* src = (c < 128) ? (W1 + c) : (W1 + 128 * 128 + (c - 128));
  ushort4 o;
  o.x = f2bf(src[(size_t)(kq + 0) * 128]);
  o.y = f2bf(src[(size_t)(kq + 1) * 128]);
  o.z = f2bf(src[(size_t)(kq + 2) * 128]);
  o.w = f2bf(src[(size_t)(kq + 3) * 128]);
  *(ushort4*)&Wt[c * 128 + kq] = o;
}

__global__ __launch_bounds__(512, 4) void node_mfma(
    const float* __restrict__ z, const unsigned short* __restrict__ Wt,
    const float* __restrict__ b1, signed char* __restrict__ gqi,
    signed char* __restrict__ gqj, float* __restrict__ sci,
    float* __restrict__ scj, int n_nodes) {
  __shared__ __align__(16) unsigned short zb[64 * 136];
  __shared__ unsigned int ep[2 * 64 * 33];
  __shared__ unsigned int smax[2][64];
  const int tid = threadIdx.x;
  const int nb = blockIdx.x * 64;

  if (tid < 128) smax[tid >> 6][tid & 63] = 0u;
#pragma unroll
  for (int i = 0; i < 4; ++i) {
    int q = tid + i * 512;
    int nl = q >> 5;
    int node = nb + nl; if (node >= n_nodes) node = n_nodes - 1;
    float4 v = ((const float4*)z)[(size_t)node * 32 + (q & 31)];
    ushort4 o;
    o.x = f2bf(v.x); o.y = f2bf(v.y); o.z = f2bf(v.z); o.w = f2bf(v.w);
    *(ushort4*)&zb[nl * 136 + (q & 31) * 4] = o;
  }
  const int w = tid >> 6, lane = tid & 63;
  const int l15 = lane & 15, quad = lane >> 4;
  short8 a[2][4];
#pragma unroll
  for (int tt = 0; tt < 2; ++tt) {
    const unsigned short* wrow =
        Wt + (size_t)((w * 2 + tt) * 16 + l15) * 128 + quad * 8;
#pragma unroll
    for (int s = 0; s < 4; ++s) a[tt][s] = *(const short8*)(wrow + s * 32);
  }
  floatx4 acc[2][4];
#pragma unroll
  for (int tt = 0; tt < 2; ++tt) {
    floatx4 bias = {0.f, 0.f, 0.f, 0.f};
    if (w < 4) {
      float4 b4 = *(const float4*)&b1[(w * 2 + tt) * 16 + quad * 4];
      bias[0] = b4.x; bias[1] = b4.y; bias[2] = b4.z; bias[3] = b4.w;
    }
#pragma unroll
    for (int nt = 0; nt < 4; ++nt) acc[tt][nt] = bias;
  }
  __syncthreads();
#pragma unroll
  for (int nt = 0; nt < 4; ++nt) {
    short8 bz[4];
#pragma unroll
    for (int s = 0; s < 4; ++s)
      bz[s] = *(const short8*)&zb[(nt * 16 + l15) * 136 + s * 32 + quad * 8];
#pragma unroll
    for (int tt = 0; tt < 2; ++tt)
#pragma unroll
      for (int s = 0; s < 4; ++s)
        acc[tt][nt] = __builtin_amdgcn_mfma_f32_16x16x32_bf16(
            a[tt][s], bz[s], acc[tt][nt], 0, 0, 0);
  }
  const int half = w >> 2;
  const int cbase = (w & 3) * 32;
#pragma unroll
  for (int nt = 0; nt < 4; ++nt) {
    float m = 0.f;
#pragma unroll
    for (int tt = 0; tt < 2; ++tt)
#pragma unroll
      for (int r = 0; r < 4; ++r) m = fmaxf(m, fabsf(acc[tt][nt][r]));
    m = fmaxf(m, __shfl_xor(m, 16));
    m = fmaxf(m, __shfl_xor(m, 32));
    if (lane < 16)
      atomicMax(&smax[half][nt * 16 + lane], __float_as_uint(m));
  }
  __syncthreads();
#pragma unroll
  for (int nt = 0; nt < 4; ++nt) {
    const int node_l = nt * 16 + l15;
    const float am = __uint_as_float(smax[half][node_l]);
    const float inv = (am > 0.f) ? 127.f / am : 0.f;
#pragma unroll
    for (int tt = 0; tt < 2; ++tt) {
      unsigned int v = 0;
#pragma unroll
      for (int r = 0; r < 4; ++r) {
        const int q = (int)rintf(acc[tt][nt][r] * inv);
        v |= ((unsigned int)(q & 0xff)) << (8 * r);
      }
      ep[half * 2112 + node_l * 33 + ((cbase + tt * 16 + quad * 4) >> 2)] = v;
    }
  }
  __syncthreads();
  {
    const int hh = tid >> 8;
    const int sub = tid & 255;
    const int nl = sub >> 2;
    const int c32 = (sub & 3) * 32;
    const int node = nb + nl;
    const unsigned int* rp = &ep[hh * 2112 + nl * 33 + (c32 >> 2)];
    uint4 o0, o1;
    o0.x = rp[0]; o0.y = rp[1]; o0.z = rp[2]; o0.w = rp[3];
    o1.x = rp[4]; o1.y = rp[5]; o1.z = rp[6]; o1.w = rp[7];
    if (node < n_nodes) {
      signed char* dq = hh ? gqj : gqi;
      uint4* gp = (uint4*)(dq + (size_t)node * 128 + c32);
      gp[0] = o0; gp[1] = o1;
    }
    if (tid < 128) {
      const int h2 = tid >> 6, n2 = tid & 63;
      const int node2 = nb + n2;
      if (node2 < n_nodes) {
        const float amv = __uint_as_float(smax[h2][n2]);
        (h2 ? scj : sci)[node2] = amv * (1.f / 127.f);
      }
    }
  }
}

__global__ __launch_bounds__(256) void edge_mlp_q(
    const int* __restrict__ e, const signed char* __restrict__ gqi,
    const signed char* __restrict__ gqj, const float* __restrict__ sci,
    const float* __restrict__ scj, const float* __restrict__ W2,
    const float* __restrict__ b2, float* __restrict__ out, int E) {
  const int p = threadIdx.x & 7;
  const float4* wv = (const float4*)W2;
  float4 W[4];
#pragma unroll
  for (int k = 0; k < 4; ++k) W[k] = wv[p * 4 + k];
  const float bias2 = b2[0];
  const int stride = gridDim.x * 32;
  for (int edge = blockIdx.x * 32 + (threadIdx.x >> 3); edge < E; edge += stride) {
    const int i = e[edge];
    const int j = e[E + edge];
    const float si = sci[i];
    const float sj = scj[j];
    const uint4 qa = ((const uint4*)(gqi + (size_t)i * 128))[p];
    const uint4 qb = ((const uint4*)(gqj + (size_t)j * 128))[p];
    const unsigned int ua[4] = {qa.x, qa.y, qa.z, qa.w};
    const unsigned int ub[4] = {qb.x, qb.y, qb.z, qb.w};
    float acc = 0.f;
#pragma unroll
    for (int k = 0; k < 4; ++k) {
      const float wk[4] = {W[k].x, W[k].y, W[k].z, W[k].w};
#pragma unroll
      for (int b = 0; b < 4; ++b) {
        const float af = (float)(int)(signed char)(ua[k] >> (8 * b));
        const float bf = (float)(int)(signed char)(ub[k] >> (8 * b));
        const float h = fmaf(si, af, sj * bf);
        acc = fmaf(fmaxf(h, 0.f), wk[b], acc);
      }
    }
    acc += __shfl_xor(acc, 1);
    acc += __shfl_xor(acc, 2);
    acc += __shfl_xor(acc, 4);
    if (p == 0) out[edge] = 1.f / (1.f + __expf(-(acc + bias2)));
  }
}

__global__ __launch_bounds__(256) void edge_direct(
    const int* __restrict__ e, const float* __restrict__ z,
    const float* __restrict__ W1, const float* __restrict__ b1,
    const float* __restrict__ W2, const float* __restrict__ b2,
    float* __restrict__ out, int E) {
  const int lane = threadIdx.x & 63;
  const int edge = (int)((blockIdx.x * 256u + threadIdx.x) >> 6);
  if (edge >= E) return;
  const int i = e[edge], j = e[E + edge];
  const float* zi = z + (size_t)i * 128;
  const float* zj = z + (size_t)j * 128;
  const int c0 = lane * 2;
  float h0 = b1[c0], h1 = b1[c0 + 1];
  for (int k = 0; k < 128; ++k) {
    float a = zi[k], b = zj[k];
    float2 wt = *(const float2*)&W1[(size_t)k * 128 + c0];
    float2 wb = *(const float2*)&W1[(size_t)(128 + k) * 128 + c0];
    h0 = fmaf(a, wt.x, h0); h1 = fmaf(a, wt.y, h1);
    h0 = fmaf(b, wb.x, h0); h1 = fmaf(b, wb.y, h1);
  }
  float s = fmaxf(h0, 0.f) * W2[c0] + fmaxf(h1, 0.f) * W2[c0 + 1];
#pragma unroll
  for (int off = 1; off < 64; off <<= 1) s += __shfl_xor(s, off);
  if (lane == 0) out[edge] = 1.f / (1.f + __expf(-(s + b2[0])));
}

extern "C" void kernel_launch(void* const* d_in, const int* in_sizes, int n_in,
                              void* d_out, int out_size, void* d_ws, size_t ws_size,
                              hipStream_t stream) {
  const float* z  = (const float*)d_in[0];
  const int*   e  = (const int*)d_in[1];
  const float* W1 = (const float*)d_in[2];
  const float* b1 = (const float*)d_in[3];
  const float* W2 = (const float*)d_in[4];
  const float* b2 = (const float*)d_in[5];
  float* out = (float*)d_out;
  const int n_nodes = in_sizes[0] / DD;  // 50000
  const int E = in_sizes[1] / 2;         // 600000

  const size_t gq_bytes = (size_t)n_nodes * DD;            // int8 rows
  const size_t sc_bytes = (size_t)n_nodes * sizeof(float);
  const size_t wt_bytes = 256 * 128 * sizeof(unsigned short);  // 64 KB
  const size_t need = 2 * gq_bytes + 2 * sc_bytes + wt_bytes;

  if (ws_size >= need && n_nodes > 0) {
    signed char* gqi = (signed char*)d_ws;
    signed char* gqj = gqi + gq_bytes;
    float* sci = (float*)((char*)d_ws + 2 * gq_bytes);
    float* scj = (float*)((char*)d_ws + 2 * gq_bytes + sc_bytes);
    unsigned short* Wt =
        (unsigned short*)((char*)d_ws + 2 * gq_bytes + 2 * sc_bytes);

    // try single cooperative dispatch
    int maxB = 0;
    hipError_t oe = hipOccupancyMaxActiveBlocksPerMultiprocessor(
        &maxB, (const void*)fused_all, 512, 0);
    int grid = 512;
    if (oe == hipSuccess && maxB > 0) {
      int cap = maxB * 256;           // 256 CUs
      if (grid > cap) grid = cap;
    }
    bool done = false;
    if (oe == hipSuccess && grid >= 16) {
      const float* z_ = z; const int* e_ = e;
      const float* W1_ = W1; const float* b1_ = b1;
      const float* W2_ = W2; const float* b2_ = b2;
      float* out_ = out;
      signed char* gqi_ = gqi; signed char* gqj_ = gqj;
      float* sci_ = sci; float* scj_ = scj;
      unsigned short* Wt_ = Wt;
      int nn = n_nodes, EE = E;
      void* args[] = {&z_, &e_, &W1_, &b1_, &W2_, &b2_, &out_,
                      &gqi_, &gqj_, &sci_, &scj_, &Wt_, &nn, &EE};
      hipError_t le = hipLaunchCooperativeKernel(
          (const void*)fused_all, dim3(grid), dim3(512), args, 0, stream);
      done = (le == hipSuccess);
    }
    if (!done) {
      // proven R12 3-kernel fallback
      wt_build<<<32, 256, 0, stream>>>(W1, Wt);
      node_mfma<<<(n_nodes + 63) / 64, 512, 0, stream>>>(z, Wt, b1, gqi, gqj,
                                                         sci, scj, n_nodes);
      edge_mlp_q<<<2048, 256, 0, stream>>>(e, gqi, gqj, sci, scj, W2, b2, out,
                                           E);
    }
  } else {
    edge_direct<<<(E + 3) / 4, 256, 0, stream>>>(e, z, W1, b1, W2, b2, out, E);
  }
}